// Round 1
// baseline (2869.321 us; speedup 1.0000x reference)
//
#include <hip/hip_runtime.h>
#include <cstdint>
#include <cstddef>

#define BATCH   4096
#define IN_DIM  1024
#define HID     16384
#define KSEL    32

// ---------------------------------------------------------------------------
// Kernel 1: encoder GEMM  C[B,H] = X[B,D] @ W_enc[H,D]^T + b_enc
// fp32, 256x128 tile, BK=32, 256 threads, 16x8 micro-tile.
//
// NUMERICS CONTRACT (do not change): per output element, fmaf over k in
// strictly ascending order with a single accumulator, then + bias. This is
// bit-identical to the round-1 kernel that passes validation. Top-k rank-32
// boundary gaps are ~0.007; any reordering (MFMA bf16x3: absmax 4.31, or
// k-splitting) flips selections vs the np reference. MFMA is unusable here.
// The 16x8 micro-tile only changes CROSS-output packing; each output's k
// chain is unchanged (kq ascending, x->y->z->w within kq).
//
// WHY 16x8 (r5 theory): the 8x8 version reads 1.0 B of LDS per FMA; at
// ~85 B/cyc/CU ds_read_b128 throughput that over-subscribes LDS 1.5x vs
// FMA issue (8 waves/CU) -> ~66% fp32-peak ceiling. 16x8 cuts LDS to
// 0.75 B/FMA, bringing LDS demand to ~parity with FMA issue.
//
// Staging: global_load_lds width=16 into ROW-MAJOR LDS tiles, 16B chunks
// XOR-swizzled by ((row>>3)&7) so compute ds_read_b128 is conflict-free.
// No register prefetch: r2/r3 showed prefetch regs balloon live ranges and
// spill acc to scratch (77GB/28GB writes). Keep staging register-free.
// a4 is loaded per-i (not 16 upfront) to keep live ranges short:
// acc 128 + b4 32 + a4 + addr ~= 190 VGPR, fits the 256 cap of (256,2).
// ---------------------------------------------------------------------------
#define BKK 32

__global__ __launch_bounds__(256, 2)
void enc_gemm(const float* __restrict__ X, const float* __restrict__ W,
              const float* __restrict__ bias, float* __restrict__ C)
{
    __shared__ __align__(16) float As[256 * BKK];   // 32 KB, row-major, swizzled
    __shared__ __align__(16) float Bs[128 * BKK];   // 16 KB

    const int bn = blockIdx.x;   // HID/128 = 128 (fast dim, shares A-panel)
    const int bm = blockIdx.y;   // BATCH/256 = 16
    const int t  = threadIdx.x;
    const int tx = t & 15;       // 8 cols each -> 128 cols
    const int ty = t >> 4;       // 0..15, 16 rows each -> 256 rows

    float acc[16][8];
#pragma unroll
    for (int i = 0; i < 16; ++i)
#pragma unroll
        for (int j = 0; j < 8; ++j) acc[i][j] = 0.f;

    const float* Xb = X + (size_t)(bm * 256) * IN_DIM;
    const float* Wb = W + (size_t)(bn * 128) * IN_DIM;

    const int bswz  = tx & 7;            // B-read key: row = tx*8+j, (row>>3)&7 = tx&7
    const int aswz0 = (ty * 2) & 7;      // A-read key for i in 0..7  (row>>3 = ty*2)
    const int aswz1 = (ty * 2 + 1) & 7;  // A-read key for i in 8..15

    for (int k0 = 0; k0 < IN_DIM; k0 += BKK) {
        // ---- stage 256x32 A (8 x 16B/thread) and 128x32 B (4 x 16B/thread).
        // LDS slot s holds row m = s>>3, global 16B-chunk (s&7)^((m>>3)&7).
        // Lane-contiguous LDS dst (s*16B) satisfies the global_load_lds
        // wave-uniform-base + lane*16 rule.
#pragma unroll
        for (int q = 0; q < 8; ++q) {
            const int s  = q * 256 + t;           // 0..2047
            const int m  = s >> 3;                // 0..255
            const int gc = (s & 7) ^ ((m >> 3) & 7);
            __builtin_amdgcn_global_load_lds(
                (const __attribute__((address_space(1))) void*)(Xb + (size_t)m * IN_DIM + k0 + gc * 4),
                (__attribute__((address_space(3))) void*)(As + s * 4), 16, 0, 0);
        }
#pragma unroll
        for (int q = 0; q < 4; ++q) {
            const int s  = q * 256 + t;           // 0..1023
            const int m  = s >> 3;                // 0..127
            const int gc = (s & 7) ^ ((m >> 3) & 7);
            __builtin_amdgcn_global_load_lds(
                (const __attribute__((address_space(1))) void*)(Wb + (size_t)m * IN_DIM + k0 + gc * 4),
                (__attribute__((address_space(3))) void*)(Bs + s * 4), 16, 0, 0);
        }
        __syncthreads();   // drains vmcnt (global_load_lds) before reads

        // ---- compute: 8 groups of 4 consecutive k, components in order
#pragma unroll
        for (int kq = 0; kq < 8; ++kq) {
            float4 b4[8];
#pragma unroll
            for (int j = 0; j < 8; ++j)
                b4[j] = *(const float4*)(Bs + (tx * 8 + j) * BKK + ((kq ^ bswz) * 4));
#pragma unroll
            for (int i = 0; i < 16; ++i) {
                const int sw = (i < 8) ? aswz0 : aswz1;   // compile-time select
                const float4 a4 = *(const float4*)(As + (ty * 16 + i) * BKK + ((kq ^ sw) * 4));
                // k ascending per output: c = 0,1,2,3 (bit-identical chain)
#pragma unroll
                for (int j = 0; j < 8; ++j) acc[i][j] = fmaf(a4.x, b4[j].x, acc[i][j]);
#pragma unroll
                for (int j = 0; j < 8; ++j) acc[i][j] = fmaf(a4.y, b4[j].y, acc[i][j]);
#pragma unroll
                for (int j = 0; j < 8; ++j) acc[i][j] = fmaf(a4.z, b4[j].z, acc[i][j]);
#pragma unroll
                for (int j = 0; j < 8; ++j) acc[i][j] = fmaf(a4.w, b4[j].w, acc[i][j]);
            }
        }
        __syncthreads();
    }

    const int col0 = bn * 128 + tx * 8;
    float bv[8];
#pragma unroll
    for (int j = 0; j < 8; ++j) bv[j] = bias[col0 + j];
#pragma unroll
    for (int i = 0; i < 16; ++i) {
        const size_t rowoff = (size_t)(bm * 256 + ty * 16 + i) * HID + col0;
        float4 o0, o1;
        o0.x = acc[i][0] + bv[0]; o0.y = acc[i][1] + bv[1];
        o0.z = acc[i][2] + bv[2]; o0.w = acc[i][3] + bv[3];
        o1.x = acc[i][4] + bv[4]; o1.y = acc[i][5] + bv[5];
        o1.z = acc[i][6] + bv[6]; o1.w = acc[i][7] + bv[7];
        *(float4*)(C + rowoff)     = o0;
        *(float4*)(C + rowoff + 4) = o1;
    }
}

// ---------------------------------------------------------------------------
// Kernel 2 (v4): per-row exact top-32 by |value|, 4-level radix select on
// abs bit pattern. Row cached in LDS (64 KB) -> global traffic = 1 read +
// 1 write. Suffix "scan" via wave shuffles (no LDS scan array / barriers).
// Levels: bits 30:23 (256), 22:15 (256), 14:7 (256), 6:0 (128).
// ---------------------------------------------------------------------------
__global__ __launch_bounds__(256)
void topk_rows(float* __restrict__ E, int* __restrict__ idx_out,
               float* __restrict__ val_out)
{
    const int row = blockIdx.x;
    float* p = E + (size_t)row * HID;
    const int t    = threadIdx.x;
    const int lane = t & 63;
    const int wid  = t >> 6;

    __shared__ __align__(16) float row_s[HID];   // 64 KB row cache
    __shared__ unsigned h8[8][257];              // lvl-0 privatized hists
    __shared__ unsigned hist[256];
    __shared__ unsigned wsum[4];
    __shared__ unsigned s_prefix;
    __shared__ int s_rank, s_eq, s_cnt;

    // async-load the whole row into LDS (lane-contiguous 16B chunks)
#pragma unroll
    for (int c = 0; c < 16; ++c) {
        const int s = c * 256 + t;
        __builtin_amdgcn_global_load_lds(
            (const __attribute__((address_space(1))) void*)(p + (size_t)s * 4),
            (__attribute__((address_space(3))) void*)(row_s + s * 4), 16, 0, 0);
    }
    for (int i = t; i < 8 * 257; i += 256) ((unsigned*)h8)[i] = 0u;
    if (t == 0) { s_rank = KSEL; s_prefix = 0u; s_eq = 0; s_cnt = 0; }
    __syncthreads();

    // ---- level 0: exponent-byte histogram into 8 privatized copies
    unsigned* myh = h8[t & 7];
#pragma unroll
    for (int c = 0; c < 16; ++c) {
        const float4 v = *(const float4*)(row_s + (c * 256 + t) * 4);
        const float vv[4] = {v.x, v.y, v.z, v.w};
#pragma unroll
        for (int j = 0; j < 4; ++j)
            atomicAdd(&myh[(__float_as_uint(vv[j]) & 0x7FFFFFFFu) >> 23], 1u);
    }
    __syncthreads();

    const int psh_arr[4]  = {31, 23, 15, 7};
    const int sh_arr[4]   = {23, 15, 7, 0};
    const unsigned msk[4] = {255u, 255u, 255u, 127u};
    const int bits_arr[4] = {8, 8, 8, 7};

#pragma unroll
    for (int lvl = 0; lvl < 4; ++lvl) {
        const int r = s_rank;
        const unsigned pfx = s_prefix;

        unsigned mycnt;
        if (lvl == 0) {
            unsigned m = 0;
#pragma unroll
            for (int c = 0; c < 8; ++c) m += h8[c][t];
            mycnt = m;                       // own bin, no barrier needed
        } else {
            hist[t] = 0u;
            __syncthreads();
            const int psh = psh_arr[lvl];
            const int sh  = sh_arr[lvl];
#pragma unroll
            for (int c = 0; c < 16; ++c) {
                const float4 v = *(const float4*)(row_s + (c * 256 + t) * 4);
                const float vv[4] = {v.x, v.y, v.z, v.w};
#pragma unroll
                for (int j = 0; j < 4; ++j) {
                    const unsigned k = __float_as_uint(vv[j]) & 0x7FFFFFFFu;
                    if ((k >> psh) == pfx)   // few matches: contention trivial
                        atomicAdd(&hist[(k >> sh) & msk[lvl]], 1u);
                }
            }
            __syncthreads();
            mycnt = hist[t];
        }

        // wave-level inclusive suffix scan of bin counts (bin index = t)
        unsigned sv = mycnt;
#pragma unroll
        for (int off = 1; off < 64; off <<= 1) {
            const unsigned u = __shfl_down(sv, off, 64);
            sv += (lane + off < 64) ? u : 0u;
        }
        if (lane == 0) wsum[wid] = sv;       // this wave's 64-bin total
        __syncthreads();
        unsigned above = 0;
        for (int ww = wid + 1; ww < 4; ++ww) above += wsum[ww];
        const unsigned suff  = sv + above;   // sum of bins >= t
        const unsigned suffn = suff - mycnt; // sum of bins >  t
        if (suff >= (unsigned)r && suffn < (unsigned)r) {  // exactly one thread
            s_rank   = r - (int)suffn;
            s_prefix = (pfx << bits_arr[lvl]) | (unsigned)t;
        }
        __syncthreads();
    }

    const unsigned vkey = s_prefix;   // exact 31-bit abs key of the 32nd largest
    const int eq_need   = s_rank;     // how many ==vkey elements to keep (>=1)

    // ---- final: mask from LDS, write global row + compact (idx,val) lists
#pragma unroll
    for (int c = 0; c < 16; ++c) {
        const int i0 = (c * 256 + t) * 4;
        const float4 v = *(const float4*)(row_s + i0);
        float vv[4] = {v.x, v.y, v.z, v.w};
#pragma unroll
        for (int j = 0; j < 4; ++j) {
            const unsigned k = __float_as_uint(vv[j]) & 0x7FFFFFFFu;
            bool keep = false;
            if (k > vkey) keep = true;
            else if (k == vkey) {
                const int slot = atomicAdd(&s_eq, 1);
                if (slot < eq_need) keep = true;
            }
            if (keep) {
                const int ls = atomicAdd(&s_cnt, 1);
                idx_out[row * KSEL + ls] = i0 + j;
                val_out[row * KSEL + ls] = vv[j];
            } else {
                vv[j] = 0.f;
            }
        }
        float4 o; o.x = vv[0]; o.y = vv[1]; o.z = vv[2]; o.w = vv[3];
        *(float4*)(p + i0) = o;
    }
}

// ---------------------------------------------------------------------------
// Kernel 3: transpose W_dec [1024,16384] -> WdT [16384,1024] (ws scratch)
// ---------------------------------------------------------------------------
__global__ __launch_bounds__(256)
void transpose_wdec(const float* __restrict__ Wd, float* __restrict__ WdT)
{
    __shared__ float tile[32][33];
    const int bx = blockIdx.x;
    const int by = blockIdx.y;
    const int t  = threadIdx.x;
    const int lx = t & 31, ly = t >> 5;
#pragma unroll
    for (int r = 0; r < 32; r += 8)
        tile[ly + r][lx] = Wd[(size_t)(by * 32 + ly + r) * HID + bx * 32 + lx];
    __syncthreads();
#pragma unroll
    for (int r = 0; r < 32; r += 8)
        WdT[(size_t)(bx * 32 + ly + r) * IN_DIM + by * 32 + lx] = tile[lx][ly + r];
}

// ---------------------------------------------------------------------------
// Kernel 4: sparse decode  decoded[b,:] = sum_i val_i * WdT[idx_i,:] + b_dec
// ---------------------------------------------------------------------------
__global__ __launch_bounds__(256)
void decode_rows(const float* __restrict__ WdT, const float* __restrict__ bd,
                 const int* __restrict__ idxs, const float* __restrict__ vals,
                 float* __restrict__ out)
{
    const int row = blockIdx.x;
    const int d   = threadIdx.x * 4;
    float4 acc = *(const float4*)(bd + d);
    for (int i = 0; i < KSEL; ++i) {
        const int   j = idxs[row * KSEL + i];
        const float v = vals[row * KSEL + i];
        const float4 w = *(const float4*)(WdT + (size_t)j * IN_DIM + d);
        acc.x = fmaf(v, w.x, acc.x);
        acc.y = fmaf(v, w.y, acc.y);
        acc.z = fmaf(v, w.z, acc.z);
        acc.w = fmaf(v, w.w, acc.w);
    }
    *(float4*)(out + (size_t)row * IN_DIM + d) = acc;
}

__global__ __launch_bounds__(256)
void decode_rows_noT(const float* __restrict__ Wd, const float* __restrict__ bd,
                     const int* __restrict__ idxs, const float* __restrict__ vals,
                     float* __restrict__ out)
{
    const int row = blockIdx.x;
    const int d0  = threadIdx.x * 4;
    float acc[4];
#pragma unroll
    for (int q = 0; q < 4; ++q) acc[q] = bd[d0 + q];
    for (int i = 0; i < KSEL; ++i) {
        const int   j = idxs[row * KSEL + i];
        const float v = vals[row * KSEL + i];
#pragma unroll
        for (int q = 0; q < 4; ++q)
            acc[q] = fmaf(v, Wd[(size_t)(d0 + q) * HID + j], acc[q]);
    }
#pragma unroll
    for (int q = 0; q < 4; ++q) out[(size_t)row * IN_DIM + d0 + q] = acc[q];
}

// ---------------------------------------------------------------------------
extern "C" void kernel_launch(void* const* d_in, const int* in_sizes, int n_in,
                              void* d_out, int out_size, void* d_ws, size_t ws_size,
                              hipStream_t stream)
{
    const float* x     = (const float*)d_in[0];
    const float* W_enc = (const float*)d_in[1];
    const float* b_enc = (const float*)d_in[2];
    const float* W_dec = (const float*)d_in[3];
    const float* b_dec = (const float*)d_in[4];

    float* out     = (float*)d_out;
    float* sparse  = out;                                // [4096][16384]
    float* decoded = out + (size_t)BATCH * HID;          // [4096][1024]

    // ws layout: [idx list 512KB][val list 512KB][WdT 64MB]
    const size_t list_bytes = (size_t)BATCH * KSEL * 4;
    const size_t wdt_bytes  = (size_t)HID * IN_DIM * 4;
    int*   idx_l = (int*)d_ws;
    float* val_l = (float*)((char*)d_ws + list_bytes);
    float* WdT   = (float*)((char*)d_ws + 2 * list_bytes);
    const bool have_wdt = ws_size >= 2 * list_bytes + wdt_bytes;

    enc_gemm<<<dim3(HID / 128, BATCH / 256), 256, 0, stream>>>(x, W_enc, b_enc, sparse);

    topk_rows<<<BATCH, 256, 0, stream>>>(sparse, idx_l, val_l);

    if (have_wdt) {
        transpose_wdec<<<dim3(HID / 32, IN_DIM / 32), 256, 0, stream>>>(W_dec, WdT);
        decode_rows<<<BATCH, 256, 0, stream>>>(WdT, b_dec, idx_l, val_l, decoded);
    } else {
        decode_rows_noT<<<BATCH, 256, 0, stream>>>(W_dec, b_dec, idx_l, val_l, decoded);
    }
}

// Round 2
// 2309.616 us; speedup vs baseline: 1.2423x; 1.2423x over previous
//
#include <hip/hip_runtime.h>
#include <cstdint>
#include <cstddef>

#define BATCH   4096
#define IN_DIM  1024
#define HID     16384
#define KSEL    32

// ---------------------------------------------------------------------------
// Kernel 1: encoder GEMM  C[B,H] = X[B,D] @ W_enc[H,D]^T + b_enc
// fp32, 128x128 tile, BK=32, 256 threads, 8x8 micro-tile, 4 blocks/CU.
//
// NUMERICS CONTRACT (do not change): per output element, fmaf over k in
// strictly ascending order with a single accumulator, then + bias. This is
// bit-identical to the round-1 kernel that passes validation. Top-k rank-32
// boundary gaps are ~0.007; any reordering (MFMA bf16x3: absmax 4.31, or
// k-splitting) flips selections vs the np reference. MFMA is unusable here.
//
// r5 POST-MORTEM (16x8 attempt): acc[16][8]=128 floats + b4 + addr > the
// 128-VGPR allocation -> acc spilled to scratch (WRITE_SIZE 357MB vs 256MB
// output). REGRESSED 1850->2600us. Lesson re-confirmed: the accumulator
// must fit comfortably; 8x8 (64 regs) is the ceiling here.
//
// r6 THEORY: FMA floor 874us, LDS-read floor 658us, but measured ~1850us
// at VALUBusy 46% / Occupancy 23% (2 waves/SIMD). Latency-bound, not
// pipe-bound: with 2 waves/SIMD nothing covers lgkmcnt waits + barrier
// drains. Fix: 4 blocks/CU via __launch_bounds__(256,4) (VGPR cap 128,
// LDS 4x32KB=128<=160KB). Compute restructured to load a4 per-i (live set
// ~115 regs: acc 64 + b4 32 + a4 4 + addr) so 128 cap doesn't spill.
//
// Staging: global_load_lds width=16 into ROW-MAJOR LDS tiles, 16B chunks
// XOR-swizzled by ((row>>3)&7) so compute ds_read_b128 is conflict-free.
// No register prefetch of global data: r2/r3 showed prefetch regs balloon
// live ranges and spill acc to scratch. Keep staging register-free.
// ---------------------------------------------------------------------------
#define BKK 32

__global__ __launch_bounds__(256, 4)
void enc_gemm(const float* __restrict__ X, const float* __restrict__ W,
              const float* __restrict__ bias, float* __restrict__ C)
{
    __shared__ __align__(16) float As[128 * BKK];   // 16 KB, row-major, swizzled
    __shared__ __align__(16) float Bs[128 * BKK];   // 16 KB

    const int bn = blockIdx.x;   // HID/128 = 128 (fast dim, shares A via cache)
    const int bm = blockIdx.y;   // BATCH/128 = 32
    const int t  = threadIdx.x;
    const int tx = t & 15;       // 8 cols each
    const int ty = t >> 4;       // 8 rows each

    float acc[8][8];
#pragma unroll
    for (int i = 0; i < 8; ++i)
#pragma unroll
        for (int j = 0; j < 8; ++j) acc[i][j] = 0.f;

    const float* Xb = X + (size_t)(bm * 128) * IN_DIM;
    const float* Wb = W + (size_t)(bn * 128) * IN_DIM;

    const int aswz = ty & 7;     // A-read swizzle key ((m>>3)&7 = ty&7)
    const int bswz = tx & 7;     // B-read swizzle key ((n>>3)&7 = tx&7)

    for (int k0 = 0; k0 < IN_DIM; k0 += BKK) {
        // ---- stage 128x32 A and B tiles: 4 x 16B per thread per matrix.
        // LDS slot s holds row m = s>>3, global 16B-chunk (s&7)^((m>>3)&7).
        // Lane-contiguous LDS dst (s*16B) satisfies the global_load_lds
        // wave-uniform-base + lane*16 rule.
#pragma unroll
        for (int q = 0; q < 4; ++q) {
            const int s  = q * 256 + t;           // 0..1023
            const int m  = s >> 3;                // 0..127
            const int gc = (s & 7) ^ ((m >> 3) & 7);
            __builtin_amdgcn_global_load_lds(
                (const __attribute__((address_space(1))) void*)(Xb + (size_t)m * IN_DIM + k0 + gc * 4),
                (__attribute__((address_space(3))) void*)(As + s * 4), 16, 0, 0);
            __builtin_amdgcn_global_load_lds(
                (const __attribute__((address_space(1))) void*)(Wb + (size_t)m * IN_DIM + k0 + gc * 4),
                (__attribute__((address_space(3))) void*)(Bs + s * 4), 16, 0, 0);
        }
        __syncthreads();   // drains vmcnt (global_load_lds) before reads

        // ---- compute: 8 groups of 4 consecutive k, components in order.
        // b4[8] up front; a4 loaded one-at-a-time per i to keep live set
        // ~115 VGPR (fits the 128 cap of launch_bounds(256,4) w/o spill).
#pragma unroll
        for (int kq = 0; kq < 8; ++kq) {
            float4 b4[8];
#pragma unroll
            for (int j = 0; j < 8; ++j)
                b4[j] = *(const float4*)(Bs + (tx * 8 + j) * BKK + ((kq ^ bswz) * 4));
#pragma unroll
            for (int i = 0; i < 8; ++i) {
                const float4 a4 = *(const float4*)(As + (ty * 8 + i) * BKK + ((kq ^ aswz) * 4));
                // k ascending per output: c = 0,1,2,3 (bit-identical chain)
#pragma unroll
                for (int j = 0; j < 8; ++j) acc[i][j] = fmaf(a4.x, b4[j].x, acc[i][j]);
#pragma unroll
                for (int j = 0; j < 8; ++j) acc[i][j] = fmaf(a4.y, b4[j].y, acc[i][j]);
#pragma unroll
                for (int j = 0; j < 8; ++j) acc[i][j] = fmaf(a4.z, b4[j].z, acc[i][j]);
#pragma unroll
                for (int j = 0; j < 8; ++j) acc[i][j] = fmaf(a4.w, b4[j].w, acc[i][j]);
            }
        }
        __syncthreads();
    }

    const int col0 = bn * 128 + tx * 8;
    float bv[8];
#pragma unroll
    for (int j = 0; j < 8; ++j) bv[j] = bias[col0 + j];
#pragma unroll
    for (int i = 0; i < 8; ++i) {
        const size_t rowoff = (size_t)(bm * 128 + ty * 8 + i) * HID + col0;
        float4 o0, o1;
        o0.x = acc[i][0] + bv[0]; o0.y = acc[i][1] + bv[1];
        o0.z = acc[i][2] + bv[2]; o0.w = acc[i][3] + bv[3];
        o1.x = acc[i][4] + bv[4]; o1.y = acc[i][5] + bv[5];
        o1.z = acc[i][6] + bv[6]; o1.w = acc[i][7] + bv[7];
        *(float4*)(C + rowoff)     = o0;
        *(float4*)(C + rowoff + 4) = o1;
    }
}

// ---------------------------------------------------------------------------
// Kernel 2 (v4): per-row exact top-32 by |value|, 4-level radix select on
// abs bit pattern. Row cached in LDS (64 KB) -> global traffic = 1 read +
// 1 write. Suffix "scan" via wave shuffles (no LDS scan array / barriers).
// Levels: bits 30:23 (256), 22:15 (256), 14:7 (256), 6:0 (128).
// ---------------------------------------------------------------------------
__global__ __launch_bounds__(256)
void topk_rows(float* __restrict__ E, int* __restrict__ idx_out,
               float* __restrict__ val_out)
{
    const int row = blockIdx.x;
    float* p = E + (size_t)row * HID;
    const int t    = threadIdx.x;
    const int lane = t & 63;
    const int wid  = t >> 6;

    __shared__ __align__(16) float row_s[HID];   // 64 KB row cache
    __shared__ unsigned h8[8][257];              // lvl-0 privatized hists
    __shared__ unsigned hist[256];
    __shared__ unsigned wsum[4];
    __shared__ unsigned s_prefix;
    __shared__ int s_rank, s_eq, s_cnt;

    // async-load the whole row into LDS (lane-contiguous 16B chunks)
#pragma unroll
    for (int c = 0; c < 16; ++c) {
        const int s = c * 256 + t;
        __builtin_amdgcn_global_load_lds(
            (const __attribute__((address_space(1))) void*)(p + (size_t)s * 4),
            (__attribute__((address_space(3))) void*)(row_s + s * 4), 16, 0, 0);
    }
    for (int i = t; i < 8 * 257; i += 256) ((unsigned*)h8)[i] = 0u;
    if (t == 0) { s_rank = KSEL; s_prefix = 0u; s_eq = 0; s_cnt = 0; }
    __syncthreads();

    // ---- level 0: exponent-byte histogram into 8 privatized copies
    unsigned* myh = h8[t & 7];
#pragma unroll
    for (int c = 0; c < 16; ++c) {
        const float4 v = *(const float4*)(row_s + (c * 256 + t) * 4);
        const float vv[4] = {v.x, v.y, v.z, v.w};
#pragma unroll
        for (int j = 0; j < 4; ++j)
            atomicAdd(&myh[(__float_as_uint(vv[j]) & 0x7FFFFFFFu) >> 23], 1u);
    }
    __syncthreads();

    const int psh_arr[4]  = {31, 23, 15, 7};
    const int sh_arr[4]   = {23, 15, 7, 0};
    const unsigned msk[4] = {255u, 255u, 255u, 127u};
    const int bits_arr[4] = {8, 8, 8, 7};

#pragma unroll
    for (int lvl = 0; lvl < 4; ++lvl) {
        const int r = s_rank;
        const unsigned pfx = s_prefix;

        unsigned mycnt;
        if (lvl == 0) {
            unsigned m = 0;
#pragma unroll
            for (int c = 0; c < 8; ++c) m += h8[c][t];
            mycnt = m;                       // own bin, no barrier needed
        } else {
            hist[t] = 0u;
            __syncthreads();
            const int psh = psh_arr[lvl];
            const int sh  = sh_arr[lvl];
#pragma unroll
            for (int c = 0; c < 16; ++c) {
                const float4 v = *(const float4*)(row_s + (c * 256 + t) * 4);
                const float vv[4] = {v.x, v.y, v.z, v.w};
#pragma unroll
                for (int j = 0; j < 4; ++j) {
                    const unsigned k = __float_as_uint(vv[j]) & 0x7FFFFFFFu;
                    if ((k >> psh) == pfx)   // few matches: contention trivial
                        atomicAdd(&hist[(k >> sh) & msk[lvl]], 1u);
                }
            }
            __syncthreads();
            mycnt = hist[t];
        }

        // wave-level inclusive suffix scan of bin counts (bin index = t)
        unsigned sv = mycnt;
#pragma unroll
        for (int off = 1; off < 64; off <<= 1) {
            const unsigned u = __shfl_down(sv, off, 64);
            sv += (lane + off < 64) ? u : 0u;
        }
        if (lane == 0) wsum[wid] = sv;       // this wave's 64-bin total
        __syncthreads();
        unsigned above = 0;
        for (int ww = wid + 1; ww < 4; ++ww) above += wsum[ww];
        const unsigned suff  = sv + above;   // sum of bins >= t
        const unsigned suffn = suff - mycnt; // sum of bins >  t
        if (suff >= (unsigned)r && suffn < (unsigned)r) {  // exactly one thread
            s_rank   = r - (int)suffn;
            s_prefix = (pfx << bits_arr[lvl]) | (unsigned)t;
        }
        __syncthreads();
    }

    const unsigned vkey = s_prefix;   // exact 31-bit abs key of the 32nd largest
    const int eq_need   = s_rank;     // how many ==vkey elements to keep (>=1)

    // ---- final: mask from LDS, write global row + compact (idx,val) lists
#pragma unroll
    for (int c = 0; c < 16; ++c) {
        const int i0 = (c * 256 + t) * 4;
        const float4 v = *(const float4*)(row_s + i0);
        float vv[4] = {v.x, v.y, v.z, v.w};
#pragma unroll
        for (int j = 0; j < 4; ++j) {
            const unsigned k = __float_as_uint(vv[j]) & 0x7FFFFFFFu;
            bool keep = false;
            if (k > vkey) keep = true;
            else if (k == vkey) {
                const int slot = atomicAdd(&s_eq, 1);
                if (slot < eq_need) keep = true;
            }
            if (keep) {
                const int ls = atomicAdd(&s_cnt, 1);
                idx_out[row * KSEL + ls] = i0 + j;
                val_out[row * KSEL + ls] = vv[j];
            } else {
                vv[j] = 0.f;
            }
        }
        float4 o; o.x = vv[0]; o.y = vv[1]; o.z = vv[2]; o.w = vv[3];
        *(float4*)(p + i0) = o;
    }
}

// ---------------------------------------------------------------------------
// Kernel 3: transpose W_dec [1024,16384] -> WdT [16384,1024] (ws scratch)
// ---------------------------------------------------------------------------
__global__ __launch_bounds__(256)
void transpose_wdec(const float* __restrict__ Wd, float* __restrict__ WdT)
{
    __shared__ float tile[32][33];
    const int bx = blockIdx.x;
    const int by = blockIdx.y;
    const int t  = threadIdx.x;
    const int lx = t & 31, ly = t >> 5;
#pragma unroll
    for (int r = 0; r < 32; r += 8)
        tile[ly + r][lx] = Wd[(size_t)(by * 32 + ly + r) * HID + bx * 32 + lx];
    __syncthreads();
#pragma unroll
    for (int r = 0; r < 32; r += 8)
        WdT[(size_t)(bx * 32 + ly + r) * IN_DIM + by * 32 + lx] = tile[lx][ly + r];
}

// ---------------------------------------------------------------------------
// Kernel 4: sparse decode  decoded[b,:] = sum_i val_i * WdT[idx_i,:] + b_dec
// ---------------------------------------------------------------------------
__global__ __launch_bounds__(256)
void decode_rows(const float* __restrict__ WdT, const float* __restrict__ bd,
                 const int* __restrict__ idxs, const float* __restrict__ vals,
                 float* __restrict__ out)
{
    const int row = blockIdx.x;
    const int d   = threadIdx.x * 4;
    float4 acc = *(const float4*)(bd + d);
    for (int i = 0; i < KSEL; ++i) {
        const int   j = idxs[row * KSEL + i];
        const float v = vals[row * KSEL + i];
        const float4 w = *(const float4*)(WdT + (size_t)j * IN_DIM + d);
        acc.x = fmaf(v, w.x, acc.x);
        acc.y = fmaf(v, w.y, acc.y);
        acc.z = fmaf(v, w.z, acc.z);
        acc.w = fmaf(v, w.w, acc.w);
    }
    *(float4*)(out + (size_t)row * IN_DIM + d) = acc;
}

__global__ __launch_bounds__(256)
void decode_rows_noT(const float* __restrict__ Wd, const float* __restrict__ bd,
                     const int* __restrict__ idxs, const float* __restrict__ vals,
                     float* __restrict__ out)
{
    const int row = blockIdx.x;
    const int d0  = threadIdx.x * 4;
    float acc[4];
#pragma unroll
    for (int q = 0; q < 4; ++q) acc[q] = bd[d0 + q];
    for (int i = 0; i < KSEL; ++i) {
        const int   j = idxs[row * KSEL + i];
        const float v = vals[row * KSEL + i];
#pragma unroll
        for (int q = 0; q < 4; ++q)
            acc[q] = fmaf(v, Wd[(size_t)(d0 + q) * HID + j], acc[q]);
    }
#pragma unroll
    for (int q = 0; q < 4; ++q) out[(size_t)row * IN_DIM + d0 + q] = acc[q];
}

// ---------------------------------------------------------------------------
extern "C" void kernel_launch(void* const* d_in, const int* in_sizes, int n_in,
                              void* d_out, int out_size, void* d_ws, size_t ws_size,
                              hipStream_t stream)
{
    const float* x     = (const float*)d_in[0];
    const float* W_enc = (const float*)d_in[1];
    const float* b_enc = (const float*)d_in[2];
    const float* W_dec = (const float*)d_in[3];
    const float* b_dec = (const float*)d_in[4];

    float* out     = (float*)d_out;
    float* sparse  = out;                                // [4096][16384]
    float* decoded = out + (size_t)BATCH * HID;          // [4096][1024]

    // ws layout: [idx list 512KB][val list 512KB][WdT 64MB]
    const size_t list_bytes = (size_t)BATCH * KSEL * 4;
    const size_t wdt_bytes  = (size_t)HID * IN_DIM * 4;
    int*   idx_l = (int*)d_ws;
    float* val_l = (float*)((char*)d_ws + list_bytes);
    float* WdT   = (float*)((char*)d_ws + 2 * list_bytes);
    const bool have_wdt = ws_size >= 2 * list_bytes + wdt_bytes;

    enc_gemm<<<dim3(HID / 128, BATCH / 128), 256, 0, stream>>>(x, W_enc, b_enc, sparse);

    topk_rows<<<BATCH, 256, 0, stream>>>(sparse, idx_l, val_l);

    if (have_wdt) {
        transpose_wdec<<<dim3(HID / 32, IN_DIM / 32), 256, 0, stream>>>(W_dec, WdT);
        decode_rows<<<BATCH, 256, 0, stream>>>(WdT, b_dec, idx_l, val_l, decoded);
    } else {
        decode_rows_noT<<<BATCH, 256, 0, stream>>>(W_dec, b_dec, idx_l, val_l, decoded);
    }
}